// Round 1
// 210.433 us; speedup vs baseline: 1.0007x; 1.0007x over previous
//
#include <hip/hip_runtime.h>
#include <math.h>

// ETM forward. B=1024 S=512 V=50000 E=300 H=800 T=50.
// ka: [fused] rhoh=bf16(rho) cast  +  zero xbar/topicsumR/loss + all B-frags
// kb: [fused] k4 betaU=exp(rhoh@alpha^T) (16v/block) + k1 sliced token gather
//     k1 gather: ballot-compaction (no serialized LDS atomics) + 8x-unrolled
//     token loop (8 independent global loads in flight -> latency-bound fix)
// k2m: hbh = bf16(relu((xbar/n)@W1+b1)) via MFMA (x-tile cast in LDS)
// k3: mu/lv via MFMA -> LDS -> softmax/theta/kl
// k6: recon + loss (one block per doc; sums topicsum replicas)

#define Bn 1024
#define Sn 512
#define Vn 50000
#define En 300
#define Hn 800
#define Tn 50
#define KP 320             // padded K for E-dim (10 tiles of 32)
#define BSTR 64            // betaU bf16 row stride (ushorts) = 128 B
#define W1FRAG_N (50 * 10 * 64 * 8)
#define WFRAG_N  (8 * 25 * 64 * 8)
#define NRANGE 8
#define VRANGE (Vn / NRANGE)
#define CASTB (Vn * (KP / 4) / 256)            // 15625 cast blocks
#define K4B (Vn / 16)                          // 3125 k4 blocks

typedef __bf16 bf16x8 __attribute__((ext_vector_type(8)));
typedef float  f32x4  __attribute__((ext_vector_type(4)));

__device__ __forceinline__ float waveReduceSum(float v) {
    #pragma unroll
    for (int off = 32; off > 0; off >>= 1) v += __shfl_xor(v, off, 64);
    return v;
}
__device__ __forceinline__ float waveReduceMax(float v) {
    #pragma unroll
    for (int off = 32; off > 0; off >>= 1) v = fmaxf(v, __shfl_xor(v, off, 64));
    return v;
}
__device__ __forceinline__ unsigned short f2bf(float x) {
    unsigned u = __float_as_uint(x);
    return (unsigned short)((u + 0x7FFFu + ((u >> 16) & 1u)) >> 16);
}
__device__ __forceinline__ float bf_lo(unsigned u) { return __uint_as_float(u << 16); }
__device__ __forceinline__ float bf_hi(unsigned u) { return __uint_as_float(u & 0xFFFF0000u); }
// popcount of (mask & lanemask_lt) for the calling lane
__device__ __forceinline__ int lane_prefix(unsigned long long m) {
    return __builtin_amdgcn_mbcnt_hi((unsigned)(m >> 32),
           __builtin_amdgcn_mbcnt_lo((unsigned)m, 0));
}

// Fused: blocks [0,CASTB) stream-cast rho->rhoh (pad to KP); the rest zero
// xbar/topicsumR/loss and build alpha/W1/[Wmu|Wlv] MFMA B-frags.
__global__ __launch_bounds__(256) void ka_init(
        const float4* __restrict__ rho4, ushort4* __restrict__ rhoh4,
        const float* __restrict__ alpha, const float* __restrict__ W1,
        const float* __restrict__ Wmu, const float* __restrict__ Wlv,
        unsigned short* __restrict__ bfrag, unsigned short* __restrict__ w1frag,
        unsigned short* __restrict__ wfrag, float* __restrict__ topicsumR,
        float* __restrict__ loss, float* __restrict__ xbar) {
    if (blockIdx.x < CASTB) {
        const int i = blockIdx.x * 256 + threadIdx.x;   // < Vn*(KP/4) exactly
        int v = i / (KP / 4), s = i - v * (KP / 4);
        ushort4 p = {0, 0, 0, 0};
        if (s < En / 4) {
            float4 r = rho4[v * (En / 4) + s];
            p.x = f2bf(r.x); p.y = f2bf(r.y); p.z = f2bf(r.z); p.w = f2bf(r.w);
        }
        rhoh4[i] = p;
        return;
    }
    const int gid = (blockIdx.x - CASTB) * 256 + threadIdx.x;
    if (gid < 512) topicsumR[gid] = 0.f;
    if (gid == 520) *loss = 0.f;
    if (gid < Bn * En) xbar[gid] = 0.f;
    if (gid < 4 * 10 * 64 * 8) {
        int j = gid & 7;
        int lane = (gid >> 3) & 63;
        int rest = gid >> 9;               // w*10 + kt
        int kt = rest % 10, w = rest / 10;
        int t = 16 * w + (lane & 15);
        int e = kt * 32 + (lane >> 4) * 8 + j;
        bfrag[gid] = (t < Tn && e < En) ? f2bf(alpha[t * En + e]) : (unsigned short)0;
    }
    if (gid < W1FRAG_N) {
        int j = gid & 7, lane = (gid >> 3) & 63, rest = gid >> 9;
        int kt = rest % 10, nt = rest / 10;
        int e = kt * 32 + (lane >> 4) * 8 + j;
        int hcol = nt * 16 + (lane & 15);
        w1frag[gid] = (e < En) ? f2bf(W1[e * Hn + hcol]) : (unsigned short)0;
    } else {
        int g2 = gid - W1FRAG_N;
        if (g2 < WFRAG_N) {
            int j = g2 & 7, lane = (g2 >> 3) & 63, rest = g2 >> 9;
            int kt = rest % 25, nt = rest / 25;
            int k = kt * 32 + (lane >> 4) * 8 + j;        // < 800 always
            int t = (nt & 3) * 16 + (lane & 15);
            float val = 0.f;
            if (t < Tn) val = (nt < 4) ? Wmu[k * Tn + t] : Wlv[k * Tn + t];
            wfrag[g2] = f2bf(val);
        }
    }
}

// Fused k4+k1: blocks [0,K4B) = betaU MFMA tiles; rest = sliced token gather.
// Co-residency overlaps k4's MFMA pipe with k1's memory latency.
__global__ __launch_bounds__(256) void kb_beta_tokens(
        const unsigned short* __restrict__ rhoh,
        const unsigned short* __restrict__ bfrag,
        unsigned int* __restrict__ betaU32, float* __restrict__ topicsumR,
        const int* __restrict__ ids, int* __restrict__ toks,
        int* __restrict__ cnt, float* __restrict__ xbar) {
    __shared__ unsigned short trans[16 * 66];   // k4 transpose (2112 B)
    __shared__ __align__(16) int sid[Sn];       // k1 range-filtered tokens
    __shared__ int sfid[Sn];                    // k1 full compaction (r==0)
    __shared__ int scount, sfull;
    const int tid = threadIdx.x;

    if (blockIdx.x < K4B) {
        // ---- k4: betaU tile (16 v), wave = topic tile ----
        const int wave = tid >> 6, lane = tid & 63;
        const int quad = lane >> 4, l15 = lane & 15;
        const int v0 = blockIdx.x * 16;
        const unsigned short* arow = rhoh + (size_t)(v0 + l15) * KP + quad * 8;
        f32x4 acc = {0.f, 0.f, 0.f, 0.f};
        #pragma unroll
        for (int kt = 0; kt < 10; ++kt) {
            bf16x8 a = *(const bf16x8*)(arow + kt * 32);
            bf16x8 bv = *(const bf16x8*)(bfrag + ((wave * 10 + kt) * 64 + lane) * 8);
            acc = __builtin_amdgcn_mfma_f32_16x16x32_bf16(a, bv, acc, 0, 0, 0);
        }
        float ts = 0.f;
        #pragma unroll
        for (int r = 0; r < 4; ++r) {
            float ev = expf(acc[r]);
            ts += ev;
            trans[(quad * 4 + r) * 66 + 16 * wave + l15] = f2bf(ev);
        }
        ts += __shfl_xor(ts, 16, 64);
        ts += __shfl_xor(ts, 32, 64);
        const int t = 16 * wave + l15;
        if (lane < 16 && t < Tn)
            atomicAdd(&topicsumR[(blockIdx.x & 7) * 64 + t], ts);
        __syncthreads();
        unsigned int* dst = betaU32 + (size_t)v0 * 32;
        const unsigned int* tr32 = (const unsigned int*)trans;
        for (int i = tid; i < 16 * 32; i += 256)
            dst[i] = tr32[(i >> 5) * 33 + (i & 31)];
        return;
    }
    // ---- k1: doc-range gather ----
    const int blk = blockIdx.x - K4B;
    const int r = blk & (NRANGE - 1), b = blk >> 3;
    const int lo = r * VRANGE, hi = lo + VRANGE;
    const int lane = tid & 63;
    if (tid == 0) { scount = 0; sfull = 0; }
    __syncthreads();
    // ballot-based compaction: one LDS atomic per wave, not per lane
    #pragma unroll
    for (int s0 = 0; s0 < Sn; s0 += 256) {
        int id = ids[b * Sn + s0 + tid];
        bool val = (id != 1 && id != 2);
        bool inr = val && id >= lo && id < hi;
        unsigned long long mb = __ballot(inr);
        int pre = lane_prefix(mb);
        int wc = __popcll(mb);
        int base = 0;
        if (lane == 0 && wc) base = atomicAdd(&scount, wc);
        base = __shfl(base, 0, 64);
        if (inr) sid[base + pre] = id;
        if (r == 0) {
            unsigned long long fb = __ballot(val);
            int fpre = lane_prefix(fb);
            int fwc = __popcll(fb);
            int fbase = 0;
            if (lane == 0 && fwc) fbase = atomicAdd(&sfull, fwc);
            fbase = __shfl(fbase, 0, 64);
            if (val) sfid[fbase + fpre] = id;
        }
    }
    __syncthreads();
    if (r == 0) {
        const int nf = sfull;
        for (int i = tid; i < nf; i += 256) toks[b * Sn + i] = sfid[i];
        if (tid == 0) cnt[b] = nf;
    }
    const int m = scount;
    const unsigned int* rhoh32 = (const unsigned int*)rhoh;
    if (tid < En / 2 && m > 0) {
        float ax = 0.f, ay = 0.f;
        int s = 0;
        // 8x unroll: 8 independent row loads in flight per lane (MLP)
        for (; s + 8 <= m; s += 8) {
            const int4 q0 = *(const int4*)&sid[s];
            const int4 q1 = *(const int4*)&sid[s + 4];
            unsigned u0 = rhoh32[q0.x * (KP / 2) + tid];
            unsigned u1 = rhoh32[q0.y * (KP / 2) + tid];
            unsigned u2 = rhoh32[q0.z * (KP / 2) + tid];
            unsigned u3 = rhoh32[q0.w * (KP / 2) + tid];
            unsigned u4 = rhoh32[q1.x * (KP / 2) + tid];
            unsigned u5 = rhoh32[q1.y * (KP / 2) + tid];
            unsigned u6 = rhoh32[q1.z * (KP / 2) + tid];
            unsigned u7 = rhoh32[q1.w * (KP / 2) + tid];
            ax += bf_lo(u0); ay += bf_hi(u0);
            ax += bf_lo(u1); ay += bf_hi(u1);
            ax += bf_lo(u2); ay += bf_hi(u2);
            ax += bf_lo(u3); ay += bf_hi(u3);
            ax += bf_lo(u4); ay += bf_hi(u4);
            ax += bf_lo(u5); ay += bf_hi(u5);
            ax += bf_lo(u6); ay += bf_hi(u6);
            ax += bf_lo(u7); ay += bf_hi(u7);
        }
        for (; s < m; ++s) {
            unsigned u = rhoh32[sid[s] * (KP / 2) + tid];
            ax += bf_lo(u); ay += bf_hi(u);
        }
        atomicAdd(&xbar[b * En + 2 * tid], ax);
        atomicAdd(&xbar[b * En + 2 * tid + 1], ay);
    }
}

// hbh = bf16(relu((xbar/n)@W1+b1)) via MFMA; x-tile normalized+cast into LDS
// (row stride 328 ushorts -> 2-way bank aliasing only = free).
__global__ __launch_bounds__(256) void k2m_h(
        const float* __restrict__ xbar, const int* __restrict__ cnt,
        const unsigned short* __restrict__ w1frag,
        const float* __restrict__ b1, unsigned short* __restrict__ hbh) {
    __shared__ unsigned short xs[16 * 328];    // 10496 B
    __shared__ float invn[16];
    const int tid = threadIdx.x;
    const int wave = tid >> 6, lane = tid & 63;
    const int quad = lane >> 4, l15 = lane & 15;
    const int b0 = blockIdx.x * 16;
    if (tid < 16) invn[tid] = 1.0f / (float)cnt[b0 + tid];
    __syncthreads();
    for (int i = tid; i < 16 * KP; i += 256) {
        int row = i / KP, e = i - row * KP;
        xs[row * 328 + e] = (e < En) ? f2bf(xbar[(b0 + row) * En + e] * invn[row])
                                     : (unsigned short)0;
    }
    __syncthreads();
    const int nt = blockIdx.y * 4 + wave;
    if (nt < 50) {
        const unsigned short* arow = xs + l15 * 328 + quad * 8;
        f32x4 acc = {0.f, 0.f, 0.f, 0.f};
        #pragma unroll
        for (int kt = 0; kt < 10; ++kt) {
            bf16x8 a = *(const bf16x8*)(arow + kt * 32);
            bf16x8 bv = *(const bf16x8*)(w1frag + ((size_t)(nt * 10 + kt) * 64 + lane) * 8);
            acc = __builtin_amdgcn_mfma_f32_16x16x32_bf16(a, bv, acc, 0, 0, 0);
        }
        const int col = nt * 16 + l15;
        const float bias = b1[col];
        #pragma unroll
        for (int r = 0; r < 4; ++r) {
            int row = b0 + quad * 4 + r;
            hbh[(size_t)row * Hn + col] = f2bf(fmaxf(acc[r] + bias, 0.f));
        }
    }
}

// mu/lv via MFMA -> LDS (stride 65) -> per-wave softmax/theta/kl epilogue.
__global__ __launch_bounds__(256) void k3_theta(
        const unsigned short* __restrict__ hbh,
        const unsigned short* __restrict__ wfrag,
        const float* __restrict__ bmu, const float* __restrict__ blv,
        float* __restrict__ theta, float* __restrict__ loss) {
    __shared__ float mlds[16 * 65];
    __shared__ float llds[16 * 65];
    const int tid = threadIdx.x;
    const int wave = tid >> 6, lane = tid & 63;
    const int quad = lane >> 4, l15 = lane & 15;
    const int b0 = blockIdx.x * 16;
    const unsigned short* arow = hbh + (size_t)(b0 + l15) * Hn + quad * 8;
    f32x4 am = {0.f, 0.f, 0.f, 0.f}, al = {0.f, 0.f, 0.f, 0.f};
    #pragma unroll
    for (int kt = 0; kt < 25; ++kt) {
        bf16x8 a  = *(const bf16x8*)(arow + kt * 32);
        bf16x8 bm = *(const bf16x8*)(wfrag + ((size_t)(wave * 25 + kt) * 64 + lane) * 8);
        bf16x8 bl = *(const bf16x8*)(wfrag + ((size_t)((4 + wave) * 25 + kt) * 64 + lane) * 8);
        am = __builtin_amdgcn_mfma_f32_16x16x32_bf16(a, bm, am, 0, 0, 0);
        al = __builtin_amdgcn_mfma_f32_16x16x32_bf16(a, bl, al, 0, 0, 0);
    }
    const int t = wave * 16 + l15;                 // 0..63 LDS col
    const float bm_ = (t < Tn) ? bmu[t] : 0.f;
    const float bl_ = (t < Tn) ? blv[t] : 0.f;
    #pragma unroll
    for (int r = 0; r < 4; ++r) {
        int row = quad * 4 + r;
        mlds[row * 65 + t] = am[r] + bm_;
        llds[row * 65 + t] = al[r] + bl_;
    }
    __syncthreads();
    const int tt = (lane < Tn) ? lane : (Tn - 1);
    const bool act = (lane < Tn);
    float klacc = 0.f;
    #pragma unroll
    for (int k = 0; k < 4; ++k) {
        int row = wave * 4 + k;
        float mu = mlds[row * 65 + tt];
        float lv = llds[row * 65 + tt];
        float m = waveReduceMax(act ? mu : -1e30f);
        float ex = act ? expf(mu - m) : 0.f;
        float ssum = waveReduceSum(ex);
        if (act) theta[(b0 + row) * Tn + lane] = ex / ssum;
        klacc += waveReduceSum(act ? (1.f + lv - mu * mu - expf(lv)) : 0.f);
    }
    if (lane == 0) atomicAdd(loss, -0.5f * klacc * (1.0f / (float)Bn));
}

// recon[b] = -sum_tok log( sum_t (theta/Z)[t] * betaU[tok,t] + 1e-5 ).
// One block per doc; Z = sum of the 8 topicsum replicas.
__global__ __launch_bounds__(256) void k6_recon(
        const int* __restrict__ toks, const int* __restrict__ cnt,
        const float* __restrict__ theta, const float* __restrict__ topicsumR,
        const unsigned short* __restrict__ betaUh, float* __restrict__ loss) {
    __shared__ float sw[Tn];
    __shared__ float swred[4];
    const int b = blockIdx.x, tid = threadIdx.x;
    if (tid < Tn) {
        float z = 0.f;
        #pragma unroll
        for (int j = 0; j < 8; ++j) z += topicsumR[j * 64 + tid];
        sw[tid] = theta[b * Tn + tid] / z;
    }
    __syncthreads();
    float wr[Tn];
    #pragma unroll
    for (int t = 0; t < Tn; ++t) wr[t] = sw[t];
    float lsum = 0.f;
    const int n = cnt[b];
    for (int i = tid; i < n; i += 256) {
        int v = toks[b * Sn + i];
        const uint4* q = (const uint4*)(betaUh + (size_t)v * BSTR);
        float dot = 0.f;
        #pragma unroll
        for (int k = 0; k < 6; ++k) {
            uint4 u = q[k];
            int t = 8 * k;
            dot += wr[t]     * bf_lo(u.x) + wr[t + 1] * bf_hi(u.x);
            dot += wr[t + 2] * bf_lo(u.y) + wr[t + 3] * bf_hi(u.y);
            dot += wr[t + 4] * bf_lo(u.z) + wr[t + 5] * bf_hi(u.z);
            dot += wr[t + 6] * bf_lo(u.w) + wr[t + 7] * bf_hi(u.w);
        }
        unsigned d = ((const unsigned*)q)[24];
        dot += wr[48] * bf_lo(d) + wr[49] * bf_hi(d);
        lsum += logf(dot + 1e-5f);
    }
    float s = waveReduceSum(lsum);
    const int wave = tid >> 6, lane = tid & 63;
    if (lane == 0) swred[wave] = s;
    __syncthreads();
    if (tid == 0) {
        float tot = swred[0] + swred[1] + swred[2] + swred[3];
        atomicAdd(loss, -tot * (1.0f / (float)Bn));
    }
}

extern "C" void kernel_launch(void* const* d_in, const int* in_sizes, int n_in,
                              void* d_out, int out_size, void* d_ws, size_t ws_size,
                              hipStream_t stream) {
    const int*   ids   = (const int*)d_in[0];
    const float* rho   = (const float*)d_in[1];
    const float* alpha = (const float*)d_in[2];
    const float* W1    = (const float*)d_in[3];
    const float* b1    = (const float*)d_in[4];
    const float* Wmu   = (const float*)d_in[5];
    const float* bmu   = (const float*)d_in[6];
    const float* Wlv   = (const float*)d_in[7];
    const float* blv   = (const float*)d_in[8];

    float* theta = (float*)d_out;            // [B, T]
    float* loss  = theta + Bn * Tn;          // scalar at d_out[51200]

    char* w = (char*)d_ws;
    float* topicsumR = (float*)w;               w += 8 * 64 * 4;
    unsigned short* bfrag = (unsigned short*)w; w += 4 * 10 * 64 * 8 * 2;
    unsigned short* w1frag = (unsigned short*)w; w += (size_t)W1FRAG_N * 2;
    unsigned short* wfrag = (unsigned short*)w;  w += (size_t)WFRAG_N * 2;
    int*   cnt      = (int*)w;                  w += Bn * 4;
    int*   toks     = (int*)w;                  w += Bn * Sn * 4;
    float* xbar     = (float*)w;                w += Bn * En * 4;
    unsigned short* hbh = (unsigned short*)w;   w += (size_t)Bn * Hn * 2;
    unsigned short* rhoh = (unsigned short*)w;  w += (size_t)Vn * KP * 2;   // 32 MB
    unsigned int* betaU32 = (unsigned int*)w;   w += (size_t)Vn * 128;      // 6.4 MB

    const int k0grid = (W1FRAG_N + WFRAG_N + 255) / 256;   // 1400
    ka_init<<<CASTB + k0grid, 256, 0, stream>>>(
        (const float4*)rho, (ushort4*)rhoh, alpha, W1, Wmu, Wlv,
        bfrag, w1frag, wfrag, topicsumR, loss, xbar);
    kb_beta_tokens<<<K4B + Bn * NRANGE, 256, 0, stream>>>(
        rhoh, bfrag, betaU32, topicsumR, ids, toks, cnt, xbar);
    k2m_h<<<dim3(64, 13), 256, 0, stream>>>(xbar, cnt, w1frag, b1, hbh);
    k3_theta<<<64, 256, 0, stream>>>(hbh, wfrag, bmu, blv, theta, loss);
    k6_recon<<<Bn, 256, 0, stream>>>(toks, cnt, theta, topicsumR,
                                     (const unsigned short*)betaU32, loss);
}

// Round 2
// 200.423 us; speedup vs baseline: 1.0507x; 1.0499x over previous
//
#include <hip/hip_runtime.h>
#include <math.h>

// ETM forward. B=1024 S=512 V=50000 E=300 H=800 T=50.
// ka: [fused] rhoh=bf16(rho) cast  +  zero topicsumR/loss + all B-frags
// kb: [fused] k4 betaU=exp(rhoh@alpha^T) (16v/block) + k1 sliced token gather
//     k1 gather: wave-token-parallel, 40 lanes x uint4 = one 640B row per
//     load inst, 4 rows in flight; partials to xbarP (plain stores, no
//     cross-XCD atomics)
// k2m: hbh = bf16(relu((sum_r xbarP/n)@W1+b1)) via MFMA (x-tile cast in LDS)
// k3: mu/lv via MFMA -> LDS -> softmax/theta/kl
// k6: recon + loss (one block per doc; sums topicsum replicas)

#define Bn 1024
#define Sn 512
#define Vn 50000
#define En 300
#define Hn 800
#define Tn 50
#define KP 320             // padded K for E-dim (10 tiles of 32)
#define BSTR 64            // betaU bf16 row stride (ushorts) = 128 B
#define W1FRAG_N (50 * 10 * 64 * 8)
#define WFRAG_N  (8 * 25 * 64 * 8)
#define NRANGE 8
#define VRANGE (Vn / NRANGE)
#define CASTB (Vn * (KP / 4) / 256)            // 15625 cast blocks
#define K4B (Vn / 16)                          // 3125 k4 blocks

typedef __bf16 bf16x8 __attribute__((ext_vector_type(8)));
typedef float  f32x4  __attribute__((ext_vector_type(4)));

__device__ __forceinline__ float waveReduceSum(float v) {
    #pragma unroll
    for (int off = 32; off > 0; off >>= 1) v += __shfl_xor(v, off, 64);
    return v;
}
__device__ __forceinline__ float waveReduceMax(float v) {
    #pragma unroll
    for (int off = 32; off > 0; off >>= 1) v = fmaxf(v, __shfl_xor(v, off, 64));
    return v;
}
__device__ __forceinline__ unsigned short f2bf(float x) {
    unsigned u = __float_as_uint(x);
    return (unsigned short)((u + 0x7FFFu + ((u >> 16) & 1u)) >> 16);
}
__device__ __forceinline__ float bf_lo(unsigned u) { return __uint_as_float(u << 16); }
__device__ __forceinline__ float bf_hi(unsigned u) { return __uint_as_float(u & 0xFFFF0000u); }
// popcount of (mask & lanemask_lt) for the calling lane
__device__ __forceinline__ int lane_prefix(unsigned long long m) {
    return __builtin_amdgcn_mbcnt_hi((unsigned)(m >> 32),
           __builtin_amdgcn_mbcnt_lo((unsigned)m, 0));
}

#define ACC8(u) { a0 += bf_lo((u).x); a1 += bf_hi((u).x); \
                  a2 += bf_lo((u).y); a3 += bf_hi((u).y); \
                  a4 += bf_lo((u).z); a5 += bf_hi((u).z); \
                  a6 += bf_lo((u).w); a7 += bf_hi((u).w); }

// Fused: blocks [0,CASTB) stream-cast rho->rhoh (pad to KP); the rest zero
// topicsumR/loss and build alpha/W1/[Wmu|Wlv] MFMA B-frags.
__global__ __launch_bounds__(256) void ka_init(
        const float4* __restrict__ rho4, ushort4* __restrict__ rhoh4,
        const float* __restrict__ alpha, const float* __restrict__ W1,
        const float* __restrict__ Wmu, const float* __restrict__ Wlv,
        unsigned short* __restrict__ bfrag, unsigned short* __restrict__ w1frag,
        unsigned short* __restrict__ wfrag, float* __restrict__ topicsumR,
        float* __restrict__ loss) {
    if (blockIdx.x < CASTB) {
        const int i = blockIdx.x * 256 + threadIdx.x;   // < Vn*(KP/4) exactly
        int v = i / (KP / 4), s = i - v * (KP / 4);
        ushort4 p = {0, 0, 0, 0};
        if (s < En / 4) {
            float4 r = rho4[v * (En / 4) + s];
            p.x = f2bf(r.x); p.y = f2bf(r.y); p.z = f2bf(r.z); p.w = f2bf(r.w);
        }
        rhoh4[i] = p;
        return;
    }
    const int gid = (blockIdx.x - CASTB) * 256 + threadIdx.x;
    if (gid < 512) topicsumR[gid] = 0.f;
    if (gid == 520) *loss = 0.f;
    if (gid < 4 * 10 * 64 * 8) {
        int j = gid & 7;
        int lane = (gid >> 3) & 63;
        int rest = gid >> 9;               // w*10 + kt
        int kt = rest % 10, w = rest / 10;
        int t = 16 * w + (lane & 15);
        int e = kt * 32 + (lane >> 4) * 8 + j;
        bfrag[gid] = (t < Tn && e < En) ? f2bf(alpha[t * En + e]) : (unsigned short)0;
    }
    if (gid < W1FRAG_N) {
        int j = gid & 7, lane = (gid >> 3) & 63, rest = gid >> 9;
        int kt = rest % 10, nt = rest / 10;
        int e = kt * 32 + (lane >> 4) * 8 + j;
        int hcol = nt * 16 + (lane & 15);
        w1frag[gid] = (e < En) ? f2bf(W1[e * Hn + hcol]) : (unsigned short)0;
    } else {
        int g2 = gid - W1FRAG_N;
        if (g2 < WFRAG_N) {
            int j = g2 & 7, lane = (g2 >> 3) & 63, rest = g2 >> 9;
            int kt = rest % 25, nt = rest / 25;
            int k = kt * 32 + (lane >> 4) * 8 + j;        // < 800 always
            int t = (nt & 3) * 16 + (lane & 15);
            float val = 0.f;
            if (t < Tn) val = (nt < 4) ? Wmu[k * Tn + t] : Wlv[k * Tn + t];
            wfrag[g2] = f2bf(val);
        }
    }
}

// Fused k4+k1: blocks [0,K4B) = betaU MFMA tiles; rest = sliced token gather.
__global__ __launch_bounds__(256) void kb_beta_tokens(
        const unsigned short* __restrict__ rhoh,
        const unsigned short* __restrict__ bfrag,
        unsigned int* __restrict__ betaU32, float* __restrict__ topicsumR,
        const int* __restrict__ ids, int* __restrict__ toks,
        int* __restrict__ cnt, float* __restrict__ xbarP) {
    __shared__ unsigned short trans[16 * 66];   // k4 transpose (2112 B)
    __shared__ __align__(16) int sid[Sn];       // k1 range-filtered tokens
    __shared__ int sfid[Sn];                    // k1 full compaction (r==0)
    __shared__ float xred[4][320];              // k1 per-wave partials (5120 B)
    __shared__ int scount, sfull;
    const int tid = threadIdx.x;
    const int wave = tid >> 6, lane = tid & 63;

    if (blockIdx.x < K4B) {
        // ---- k4: betaU tile (16 v), wave = topic tile ----
        const int quad = lane >> 4, l15 = lane & 15;
        const int v0 = blockIdx.x * 16;
        const unsigned short* arow = rhoh + (size_t)(v0 + l15) * KP + quad * 8;
        f32x4 acc = {0.f, 0.f, 0.f, 0.f};
        #pragma unroll
        for (int kt = 0; kt < 10; ++kt) {
            bf16x8 a = *(const bf16x8*)(arow + kt * 32);
            bf16x8 bv = *(const bf16x8*)(bfrag + ((wave * 10 + kt) * 64 + lane) * 8);
            acc = __builtin_amdgcn_mfma_f32_16x16x32_bf16(a, bv, acc, 0, 0, 0);
        }
        float ts = 0.f;
        #pragma unroll
        for (int r = 0; r < 4; ++r) {
            float ev = expf(acc[r]);
            ts += ev;
            trans[(quad * 4 + r) * 66 + 16 * wave + l15] = f2bf(ev);
        }
        ts += __shfl_xor(ts, 16, 64);
        ts += __shfl_xor(ts, 32, 64);
        const int t = 16 * wave + l15;
        if (lane < 16 && t < Tn)
            atomicAdd(&topicsumR[(blockIdx.x & 7) * 64 + t], ts);
        __syncthreads();
        unsigned int* dst = betaU32 + (size_t)v0 * 32;
        const unsigned int* tr32 = (const unsigned int*)trans;
        for (int i = tid; i < 16 * 32; i += 256)
            dst[i] = tr32[(i >> 5) * 33 + (i & 31)];
        return;
    }
    // ---- k1: doc-range gather ----
    const int blk = blockIdx.x - K4B;
    const int r = blk & (NRANGE - 1), b = blk >> 3;
    const int lo = r * VRANGE, hi = lo + VRANGE;
    if (tid == 0) { scount = 0; sfull = 0; }
    __syncthreads();
    // ballot-based compaction: one LDS atomic per wave, not per lane
    #pragma unroll
    for (int s0 = 0; s0 < Sn; s0 += 256) {
        int id = ids[b * Sn + s0 + tid];
        bool val = (id != 1 && id != 2);
        bool inr = val && id >= lo && id < hi;
        unsigned long long mb = __ballot(inr);
        int pre = lane_prefix(mb);
        int wc = __popcll(mb);
        int base = 0;
        if (lane == 0 && wc) base = atomicAdd(&scount, wc);
        base = __shfl(base, 0, 64);
        if (inr) sid[base + pre] = id;
        if (r == 0) {
            unsigned long long fb = __ballot(val);
            int fpre = lane_prefix(fb);
            int fwc = __popcll(fb);
            int fbase = 0;
            if (lane == 0 && fwc) fbase = atomicAdd(&sfull, fwc);
            fbase = __shfl(fbase, 0, 64);
            if (val) sfid[fbase + fpre] = id;
        }
    }
    __syncthreads();
    if (r == 0) {
        const int nf = sfull;
        for (int i = tid; i < nf; i += 256) toks[b * Sn + i] = sfid[i];
        if (tid == 0) cnt[b] = nf;
    }
    const int m = scount;
    // wave-token-parallel gather: wave w takes tokens s = w, w+4, ...;
    // lanes 0..39 each load one uint4 (16B) -> whole 640B row per load inst.
    float a0 = 0.f, a1 = 0.f, a2 = 0.f, a3 = 0.f;
    float a4 = 0.f, a5 = 0.f, a6 = 0.f, a7 = 0.f;
    if (lane < 40) {
        const uint4* rb = (const uint4*)rhoh;     // row stride = 40 uint4
        int s = wave;
        for (; s + 12 < m; s += 16) {
            int i0 = sid[s], i1 = sid[s + 4], i2 = sid[s + 8], i3 = sid[s + 12];
            uint4 u0 = rb[(size_t)i0 * 40 + lane];
            uint4 u1 = rb[(size_t)i1 * 40 + lane];
            uint4 u2 = rb[(size_t)i2 * 40 + lane];
            uint4 u3 = rb[(size_t)i3 * 40 + lane];
            ACC8(u0); ACC8(u1); ACC8(u2); ACC8(u3);
        }
        for (; s < m; s += 4) {
            uint4 u = rb[(size_t)sid[s] * 40 + lane];
            ACC8(u);
        }
        float* xw = &xred[wave][lane * 8];
        xw[0] = a0; xw[1] = a1; xw[2] = a2; xw[3] = a3;
        xw[4] = a4; xw[5] = a5; xw[6] = a6; xw[7] = a7;
    }
    __syncthreads();
    float* xbp = xbarP + ((size_t)b * NRANGE + r) * KP;
    for (int c = tid; c < KP; c += 256)
        xbp[c] = xred[0][c] + xred[1][c] + xred[2][c] + xred[3][c];
}

// hbh = bf16(relu(((sum_r xbarP)/n)@W1+b1)) via MFMA; x-tile cast into LDS
// (row stride 328 ushorts -> 2-way bank aliasing only = free).
__global__ __launch_bounds__(256) void k2m_h(
        const float* __restrict__ xbarP, const int* __restrict__ cnt,
        const unsigned short* __restrict__ w1frag,
        const float* __restrict__ b1, unsigned short* __restrict__ hbh) {
    __shared__ unsigned short xs[16 * 328];    // 10496 B
    __shared__ float invn[16];
    const int tid = threadIdx.x;
    const int wave = tid >> 6, lane = tid & 63;
    const int quad = lane >> 4, l15 = lane & 15;
    const int b0 = blockIdx.x * 16;
    if (tid < 16) invn[tid] = 1.0f / (float)cnt[b0 + tid];
    __syncthreads();
    for (int i = tid; i < 16 * (KP / 4); i += 256) {
        int row = i / (KP / 4), e4 = (i - row * (KP / 4)) * 4;
        const float* bp = xbarP + ((size_t)(b0 + row) * NRANGE) * KP + e4;
        float sx = 0.f, sy = 0.f, sz = 0.f, sw_ = 0.f;
        #pragma unroll
        for (int rr = 0; rr < NRANGE; ++rr) {
            float4 v = *(const float4*)(bp + rr * KP);
            sx += v.x; sy += v.y; sz += v.z; sw_ += v.w;
        }
        float in = invn[row];
        ushort4 o;
        o.x = f2bf(sx * in); o.y = f2bf(sy * in);
        o.z = f2bf(sz * in); o.w = f2bf(sw_ * in);
        *(ushort4*)&xs[row * 328 + e4] = o;
    }
    __syncthreads();
    const int nt = blockIdx.y * 4 + wave;
    if (nt < 50) {
        const unsigned short* arow = xs + l15 * 328 + quad * 8;
        f32x4 acc = {0.f, 0.f, 0.f, 0.f};
        #pragma unroll
        for (int kt = 0; kt < 10; ++kt) {
            bf16x8 a = *(const bf16x8*)(arow + kt * 32);
            bf16x8 bv = *(const bf16x8*)(w1frag + ((size_t)(nt * 10 + kt) * 64 + lane) * 8);
            acc = __builtin_amdgcn_mfma_f32_16x16x32_bf16(a, bv, acc, 0, 0, 0);
        }
        const int col = nt * 16 + l15;
        const float bias = b1[col];
        #pragma unroll
        for (int r = 0; r < 4; ++r) {
            int row = b0 + quad * 4 + r;
            hbh[(size_t)row * Hn + col] = f2bf(fmaxf(acc[r] + bias, 0.f));
        }
    }
}

// mu/lv via MFMA -> LDS (stride 65) -> per-wave softmax/theta/kl epilogue.
__global__ __launch_bounds__(256) void k3_theta(
        const unsigned short* __restrict__ hbh,
        const unsigned short* __restrict__ wfrag,
        const float* __restrict__ bmu, const float* __restrict__ blv,
        float* __restrict__ theta, float* __restrict__ loss) {
    __shared__ float mlds[16 * 65];
    __shared__ float llds[16 * 65];
    const int tid = threadIdx.x;
    const int wave = tid >> 6, lane = tid & 63;
    const int quad = lane >> 4, l15 = lane & 15;
    const int b0 = blockIdx.x * 16;
    const unsigned short* arow = hbh + (size_t)(b0 + l15) * Hn + quad * 8;
    f32x4 am = {0.f, 0.f, 0.f, 0.f}, al = {0.f, 0.f, 0.f, 0.f};
    #pragma unroll
    for (int kt = 0; kt < 25; ++kt) {
        bf16x8 a  = *(const bf16x8*)(arow + kt * 32);
        bf16x8 bm = *(const bf16x8*)(wfrag + ((size_t)(wave * 25 + kt) * 64 + lane) * 8);
        bf16x8 bl = *(const bf16x8*)(wfrag + ((size_t)((4 + wave) * 25 + kt) * 64 + lane) * 8);
        am = __builtin_amdgcn_mfma_f32_16x16x32_bf16(a, bm, am, 0, 0, 0);
        al = __builtin_amdgcn_mfma_f32_16x16x32_bf16(a, bl, al, 0, 0, 0);
    }
    const int t = wave * 16 + l15;                 // 0..63 LDS col
    const float bm_ = (t < Tn) ? bmu[t] : 0.f;
    const float bl_ = (t < Tn) ? blv[t] : 0.f;
    #pragma unroll
    for (int r = 0; r < 4; ++r) {
        int row = quad * 4 + r;
        mlds[row * 65 + t] = am[r] + bm_;
        llds[row * 65 + t] = al[r] + bl_;
    }
    __syncthreads();
    const int tt = (lane < Tn) ? lane : (Tn - 1);
    const bool act = (lane < Tn);
    float klacc = 0.f;
    #pragma unroll
    for (int k = 0; k < 4; ++k) {
        int row = wave * 4 + k;
        float mu = mlds[row * 65 + tt];
        float lv = llds[row * 65 + tt];
        float m = waveReduceMax(act ? mu : -1e30f);
        float ex = act ? expf(mu - m) : 0.f;
        float ssum = waveReduceSum(ex);
        if (act) theta[(b0 + row) * Tn + lane] = ex / ssum;
        klacc += waveReduceSum(act ? (1.f + lv - mu * mu - expf(lv)) : 0.f);
    }
    if (lane == 0) atomicAdd(loss, -0.5f * klacc * (1.0f / (float)Bn));
}

// recon[b] = -sum_tok log( sum_t (theta/Z)[t] * betaU[tok,t] + 1e-5 ).
// One block per doc; Z = sum of the 8 topicsum replicas.
__global__ __launch_bounds__(256) void k6_recon(
        const int* __restrict__ toks, const int* __restrict__ cnt,
        const float* __restrict__ theta, const float* __restrict__ topicsumR,
        const unsigned short* __restrict__ betaUh, float* __restrict__ loss) {
    __shared__ float sw[Tn];
    __shared__ float swred[4];
    const int b = blockIdx.x, tid = threadIdx.x;
    if (tid < Tn) {
        float z = 0.f;
        #pragma unroll
        for (int j = 0; j < 8; ++j) z += topicsumR[j * 64 + tid];
        sw[tid] = theta[b * Tn + tid] / z;
    }
    __syncthreads();
    float wr[Tn];
    #pragma unroll
    for (int t = 0; t < Tn; ++t) wr[t] = sw[t];
    float lsum = 0.f;
    const int n = cnt[b];
    for (int i = tid; i < n; i += 256) {
        int v = toks[b * Sn + i];
        const uint4* q = (const uint4*)(betaUh + (size_t)v * BSTR);
        float dot = 0.f;
        #pragma unroll
        for (int k = 0; k < 6; ++k) {
            uint4 u = q[k];
            int t = 8 * k;
            dot += wr[t]     * bf_lo(u.x) + wr[t + 1] * bf_hi(u.x);
            dot += wr[t + 2] * bf_lo(u.y) + wr[t + 3] * bf_hi(u.y);
            dot += wr[t + 4] * bf_lo(u.z) + wr[t + 5] * bf_hi(u.z);
            dot += wr[t + 6] * bf_lo(u.w) + wr[t + 7] * bf_hi(u.w);
        }
        unsigned d = ((const unsigned*)q)[24];
        dot += wr[48] * bf_lo(d) + wr[49] * bf_hi(d);
        lsum += logf(dot + 1e-5f);
    }
    float s = waveReduceSum(lsum);
    const int wave = tid >> 6, lane = tid & 63;
    if (lane == 0) swred[wave] = s;
    __syncthreads();
    if (tid == 0) {
        float tot = swred[0] + swred[1] + swred[2] + swred[3];
        atomicAdd(loss, -tot * (1.0f / (float)Bn));
    }
}

extern "C" void kernel_launch(void* const* d_in, const int* in_sizes, int n_in,
                              void* d_out, int out_size, void* d_ws, size_t ws_size,
                              hipStream_t stream) {
    const int*   ids   = (const int*)d_in[0];
    const float* rho   = (const float*)d_in[1];
    const float* alpha = (const float*)d_in[2];
    const float* W1    = (const float*)d_in[3];
    const float* b1    = (const float*)d_in[4];
    const float* Wmu   = (const float*)d_in[5];
    const float* bmu   = (const float*)d_in[6];
    const float* Wlv   = (const float*)d_in[7];
    const float* blv   = (const float*)d_in[8];

    float* theta = (float*)d_out;            // [B, T]
    float* loss  = theta + Bn * Tn;          // scalar at d_out[51200]

    char* w = (char*)d_ws;
    float* topicsumR = (float*)w;               w += 8 * 64 * 4;
    unsigned short* bfrag = (unsigned short*)w; w += 4 * 10 * 64 * 8 * 2;
    unsigned short* w1frag = (unsigned short*)w; w += (size_t)W1FRAG_N * 2;
    unsigned short* wfrag = (unsigned short*)w;  w += (size_t)WFRAG_N * 2;
    int*   cnt      = (int*)w;                  w += Bn * 4;
    int*   toks     = (int*)w;                  w += Bn * Sn * 4;
    float* xbarP    = (float*)w;                w += (size_t)Bn * NRANGE * KP * 4; // 10.5 MB
    unsigned short* hbh = (unsigned short*)w;   w += (size_t)Bn * Hn * 2;
    unsigned short* rhoh = (unsigned short*)w;  w += (size_t)Vn * KP * 2;   // 32 MB
    unsigned int* betaU32 = (unsigned int*)w;   w += (size_t)Vn * 128;      // 6.4 MB

    const int k0grid = (W1FRAG_N + WFRAG_N + 255) / 256;   // 1400
    ka_init<<<CASTB + k0grid, 256, 0, stream>>>(
        (const float4*)rho, (ushort4*)rhoh, alpha, W1, Wmu, Wlv,
        bfrag, w1frag, wfrag, topicsumR, loss);
    kb_beta_tokens<<<K4B + Bn * NRANGE, 256, 0, stream>>>(
        rhoh, bfrag, betaU32, topicsumR, ids, toks, cnt, xbarP);
    k2m_h<<<dim3(64, 13), 256, 0, stream>>>(xbarP, cnt, w1frag, b1, hbh);
    k3_theta<<<64, 256, 0, stream>>>(hbh, wfrag, bmu, blv, theta, loss);
    k6_recon<<<Bn, 256, 0, stream>>>(toks, cnt, theta, topicsumR,
                                     (const unsigned short*)betaU32, loss);
}